// Round 1
// baseline (2995.022 us; speedup 1.0000x reference)
//
#include <hip/hip_runtime.h>

// Problem constants (fixed shapes from reference)
#define QN 8
#define KN 1024
#define DN 256
#define NROWS_TOTAL 32768          // 32*1024
#define ROWS 32                    // rows per block
#define IDX_BASE 8388608           // 32*1024*256
#define IDX_N 262144               // 8*32*1024
#define LOSS_OFF (IDX_BASE + IDX_N)

// numpy pairwise sum-of-squares over 256 contiguous floats:
// n=256 -> pairwise(128)+pairwise(128); n<=128 -> 8-accumulator unrolled loop,
// combined as ((r0+r1)+(r2+r3))+((r4+r5)+(r6+r7)). __fmul_rn/__fadd_rn block
// FMA contraction so rounding matches np (mul then add, separately rounded).
__device__ __forceinline__ float sum256_sq_np(const float* p) {
  float h[2];
#pragma unroll
  for (int half = 0; half < 2; ++half) {
    const float* a = p + half * 128;
    float r[8];
#pragma unroll
    for (int j = 0; j < 8; ++j) r[j] = __fmul_rn(a[j], a[j]);
    for (int i = 8; i < 128; i += 8) {
#pragma unroll
      for (int j = 0; j < 8; ++j) r[j] = __fadd_rn(r[j], __fmul_rn(a[i + j], a[i + j]));
    }
    h[half] = __fadd_rn(__fadd_rn(__fadd_rn(r[0], r[1]), __fadd_rn(r[2], r[3])),
                        __fadd_rn(__fadd_rn(r[4], r[5]), __fadd_rn(r[6], r[7])));
  }
  return __fadd_rn(h[0], h[1]);
}

// Prep: zero the 8 loss accumulators; precompute ||cb_k||^2 (np summation order)
__global__ void rvq_prep(const float* __restrict__ cb, float* __restrict__ ws) {
  int g = blockIdx.x * blockDim.x + threadIdx.x;
  if (g < 8) ws[g] = 0.f;
  if (g < QN * KN) ws[8 + g] = sum256_sq_np(cb + (size_t)g * DN);
}

__global__ __launch_bounds__(256, 2) void rvq_main(const float* __restrict__ z,
                                                   const float* __restrict__ cb,
                                                   float* __restrict__ ws,
                                                   float* __restrict__ out) {
  // LDS: R 32x260 (pad 4: row stride 260 breaks 256-float bank aliasing,
  // stays 16B aligned), C chunk 128 codes x 68 (64 d + pad 4), reduce bufs.
  __shared__ float Rs[ROWS * 260];
  __shared__ float Cs[128 * 68];
  __shared__ float As[ROWS];
  __shared__ float redb[ROWS * 32];
  __shared__ int   redi[ROWS * 32];
  __shared__ int   idxs[ROWS];

  const int tid = threadIdx.x;
  const int row0 = blockIdx.x * ROWS;
  const int rg = tid >> 5;    // 0..7  : 4 rows each
  const int cg = tid & 31;    // 0..31 : 4 codes each
  const int urow = tid >> 3;  // 0..31 : update-phase row
  const int udg = tid & 7;    // 0..7  : update-phase 32-dim slice

  const float* __restrict__ cnorm = ws + 8;
  float* __restrict__ wsloss = ws;

  float4* R4 = (float4*)Rs;
  float4* C4 = (float4*)Cs;
  const float4* z4 = (const float4*)z;

  // Stage z rows -> LDS residual (bit-exact copy)
#pragma unroll
  for (int t = 0; t < 8; ++t) {
    int L = t * 256 + tid;          // f4 index 0..2047
    int r = L >> 6, c4 = L & 63;
    R4[r * 65 + c4] = z4[(size_t)(row0 + r) * 64 + c4];
  }

  float4 qa[8];                     // quantized accumulator (this thread's 32 dims)
#pragma unroll
  for (int t = 0; t < 8; ++t) qa[t] = make_float4(0.f, 0.f, 0.f, 0.f);

  for (int q = 0; q < QN; ++q) {
    __syncthreads();                // residual stable
    if (tid < ROWS) As[tid] = sum256_sq_np(&Rs[tid * 260]);  // np-exact ||r||^2

    float best[4]; int bidx[4];
#pragma unroll
    for (int i = 0; i < 4; ++i) { best[i] = 3.402823466e+38f; bidx[i] = 0; }

    for (int kc = 0; kc < 8; ++kc) {      // 128-code chunks
      float acc[4][4];
#pragma unroll
      for (int i = 0; i < 4; ++i)
#pragma unroll
        for (int j = 0; j < 4; ++j) acc[i][j] = 0.f;

      for (int dc = 0; dc < 4; ++dc) {    // 64-dim chunks
        __syncthreads();
        const float4* cb4 = (const float4*)(cb + ((size_t)q * KN + kc * 128) * DN);
#pragma unroll
        for (int t = 0; t < 8; ++t) {
          int L = t * 256 + tid;          // 0..2047
          int cc = L >> 4, c4 = L & 15;
          C4[cc * 17 + c4] = cb4[cc * 64 + dc * 16 + c4];
        }
        __syncthreads();
#pragma unroll 4
        for (int d4 = 0; d4 < 16; ++d4) {
          float4 rv[4], cv[4];
#pragma unroll
          for (int i = 0; i < 4; ++i) rv[i] = R4[(rg * 4 + i) * 65 + dc * 16 + d4];
#pragma unroll
          for (int j = 0; j < 4; ++j) cv[j] = C4[(cg * 4 + j) * 17 + d4];
#pragma unroll
          for (int i = 0; i < 4; ++i)
#pragma unroll
            for (int j = 0; j < 4; ++j) {
              acc[i][j] = fmaf(rv[i].x, cv[j].x, acc[i][j]);
              acc[i][j] = fmaf(rv[i].y, cv[j].y, acc[i][j]);
              acc[i][j] = fmaf(rv[i].z, cv[j].z, acc[i][j]);
              acc[i][j] = fmaf(rv[i].w, cv[j].w, acc[i][j]);
            }
        }
      }
      // dist = fl(fl(A - 2B) + C); ascending k + strict < => lowest-index ties
#pragma unroll
      for (int j = 0; j < 4; ++j) {
        int k = kc * 128 + cg * 4 + j;
        float cn = cnorm[q * KN + k];
#pragma unroll
        for (int i = 0; i < 4; ++i) {
          float d = __fadd_rn(__fadd_rn(As[rg * 4 + i], -2.0f * acc[i][j]), cn);
          if (d < best[i]) { best[i] = d; bidx[i] = k; }
        }
      }
    }

    __syncthreads();
#pragma unroll
    for (int i = 0; i < 4; ++i) {
      redb[(rg * 4 + i) * 32 + cg] = best[i];
      redi[(rg * 4 + i) * 32 + cg] = bidx[i];
    }
    __syncthreads();
    if (tid < ROWS) {
      float b = redb[tid * 32]; int bi = redi[tid * 32];
      for (int c = 1; c < 32; ++c) {
        float v = redb[tid * 32 + c]; int vi = redi[tid * 32 + c];
        if (v < b || (v == b && vi < bi)) { b = v; bi = vi; }
      }
      idxs[tid] = bi;
      out[IDX_BASE + (size_t)q * NROWS_TOTAL + row0 + tid] = (float)bi;
    }
    __syncthreads();

    // Update phase: replicate np elementwise ops bit-exactly.
    // t = fl(q - r); qst = fl(r + t); quant += qst; r = fl(r - qst);
    // loss term = t*t (tolerance on loss is loose; order-free accumulation ok)
    int myidx = idxs[urow];
    const float4* qv4 = (const float4*)(cb + ((size_t)q * KN + myidx) * DN);
    float lp = 0.f;
#pragma unroll
    for (int t = 0; t < 8; ++t) {
      int d4 = udg * 8 + t;
      float4 qv = qv4[d4];
      float4 r = R4[urow * 65 + d4];
      float tx = __fadd_rn(qv.x, -r.x);
      float ty = __fadd_rn(qv.y, -r.y);
      float tz = __fadd_rn(qv.z, -r.z);
      float tw = __fadd_rn(qv.w, -r.w);
      float sx = __fadd_rn(r.x, tx);
      float sy = __fadd_rn(r.y, ty);
      float sz = __fadd_rn(r.z, tz);
      float sw = __fadd_rn(r.w, tw);
      qa[t].x = __fadd_rn(qa[t].x, sx);
      qa[t].y = __fadd_rn(qa[t].y, sy);
      qa[t].z = __fadd_rn(qa[t].z, sz);
      qa[t].w = __fadd_rn(qa[t].w, sw);
      float4 rn;
      rn.x = __fadd_rn(r.x, -sx);
      rn.y = __fadd_rn(r.y, -sy);
      rn.z = __fadd_rn(r.z, -sz);
      rn.w = __fadd_rn(r.w, -sw);
      R4[urow * 65 + d4] = rn;
      lp = fmaf(tx, tx, lp); lp = fmaf(ty, ty, lp);
      lp = fmaf(tz, tz, lp); lp = fmaf(tw, tw, lp);
    }
#pragma unroll
    for (int off = 32; off > 0; off >>= 1) lp += __shfl_down(lp, off, 64);
    if ((tid & 63) == 0) atomicAdd(&wsloss[q], lp);
  }

  // quantized out (each thread owns row urow, dims udg*32..+32)
#pragma unroll
  for (int t = 0; t < 8; ++t) {
    ((float4*)out)[(size_t)(row0 + urow) * 64 + udg * 8 + t] = qa[t];
  }
}

// vq_loss = sum_q fl(m + 0.25*m), m = fl(sum_sq/8388608)
__global__ void rvq_fin(const float* __restrict__ ws, float* __restrict__ out) {
  if (blockIdx.x == 0 && threadIdx.x == 0) {
    float vq = 0.f;
    for (int q = 0; q < QN; ++q) {
      float m = ws[q] / 8388608.0f;
      float l = __fadd_rn(m, 0.25f * m);
      vq = __fadd_rn(vq, l);
    }
    out[LOSS_OFF] = vq;
  }
}

extern "C" void kernel_launch(void* const* d_in, const int* in_sizes, int n_in,
                              void* d_out, int out_size, void* d_ws, size_t ws_size,
                              hipStream_t stream) {
  const float* z  = (const float*)d_in[0];
  const float* cb = (const float*)d_in[1];
  float* out = (float*)d_out;
  float* ws  = (float*)d_ws;   // [0..8): loss sums, [8..8200): codebook norms

  hipLaunchKernelGGL(rvq_prep, dim3(32), dim3(256), 0, stream, cb, ws);
  hipLaunchKernelGGL(rvq_main, dim3(NROWS_TOTAL / ROWS), dim3(256), 0, stream,
                     z, cb, ws, out);
  hipLaunchKernelGGL(rvq_fin, dim3(1), dim3(64), 0, stream, ws, out);
}